// Round 4
// baseline (252.903 us; speedup 1.0000x reference)
//
#include <hip/hip_runtime.h>
#include <stdint.h>

#define P_DIM 256
#define NREF  4096
#define NIN   8192
#define DF    512

// fused tiling
#define BJ     64                 // j-columns per block
#define TI     128                // i per inner tile
#define ISPLIT 4                  // split of the i range (outer K of GEMM2)
#define IR     (NREF / ISPLIT)    // 1024 i per block

typedef __bf16 bf16x8 __attribute__((ext_vector_type(8)));
typedef float  f32x4  __attribute__((ext_vector_type(4)));

static __device__ __forceinline__ unsigned short f2bf(float f) {
    uint32_t u = __builtin_bit_cast(uint32_t, f);
    u += 0x7FFFu + ((u >> 16) & 1u);
    return (unsigned short)(u >> 16);
}
static __device__ __forceinline__ float bf2f(unsigned short u) {
    return __builtin_bit_cast(float, (uint32_t)u << 16);
}

// casts all three fp32 arrays to bf16 (vectorized x4)
__global__ void cast3(const float* __restrict__ s0, unsigned short* __restrict__ d0, int n0,
                      const float* __restrict__ s1, unsigned short* __restrict__ d1, int n1,
                      const float* __restrict__ s2, unsigned short* __restrict__ d2, int n2) {
    int total = n0 + n1 + n2;
    int stride = gridDim.x * blockDim.x;
    for (int i = blockIdx.x * blockDim.x + threadIdx.x; i < total; i += stride) {
        const float4* s; ushort4* d; int j = i;
        if (j < n0) { s = (const float4*)s0; d = (ushort4*)d0; }
        else if ((j -= n0) < n1) { s = (const float4*)s1; d = (ushort4*)d1; }
        else { j -= n1; s = (const float4*)s2; d = (ushort4*)d2; }
        float4 v = s[j];
        ushort4 o;
        o.x = f2bf(v.x); o.y = f2bf(v.y); o.z = f2bf(v.z); o.w = f2bf(v.w);
        d[j] = o;
    }
}

// out += sum of 3 bf16 partials (each partElems elements)
__global__ void reduce3(float* __restrict__ out, const unsigned short* __restrict__ parts,
                        int n4, size_t partElems) {
    int i = blockIdx.x * blockDim.x + threadIdx.x;
    if (i >= n4) return;
    float4 a = ((const float4*)out)[i];
    const ushort4* p0 = (const ushort4*)(parts);
    const ushort4* p1 = (const ushort4*)(parts + partElems);
    const ushort4* p2 = (const ushort4*)(parts + 2 * partElems);
    ushort4 u0 = p0[i], u1 = p1[i], u2 = p2[i];
    a.x += bf2f(u0.x) + bf2f(u1.x) + bf2f(u2.x);
    a.y += bf2f(u0.y) + bf2f(u1.y) + bf2f(u2.y);
    a.z += bf2f(u0.z) + bf2f(u1.z) + bf2f(u2.z);
    a.w += bf2f(u0.w) + bf2f(u1.w) + bf2f(u2.w);
    ((float4*)out)[i] = a;
}

// Fused: per block (j-tile of 64, i-range of 1024):
//   loop i-tiles of 128:
//     phase A: T[j,i] = (Z[j]==Zr[i]) ? (desc_j . xref_i)^2 : 0   (g1 structure)
//     write T -> LDS Tl (bf16, 16B-chunk XOR swizzle)
//     phase B: accY[p, j] += Alpha[p, i-tile] @ Tl^T   (Alpha frags from L2)
//   epilogue: z==0 -> fp32 to out; z>0 -> bf16 partial slice.
__global__ __launch_bounds__(256) void fused_y(
    const unsigned short* __restrict__ Db,   // desc bf16 [NIN, DF]
    const unsigned short* __restrict__ Xb,   // X_ref bf16 [NREF, DF]
    const unsigned short* __restrict__ Ab,   // Alpha bf16 [P, NREF]
    const int* __restrict__ Z,               // [NIN]
    const int* __restrict__ Zr,              // [NREF]
    float* __restrict__ outp,                // [P, NIN]
    unsigned short* __restrict__ part)       // [(ISPLIT-1) * P * NIN] bf16
{
    constexpr int BK = 64;
    __shared__ unsigned short tA[BJ * BK];    // desc tile (rows j)
    __shared__ unsigned short tB[TI * BK];    // X tile (rows i)
    __shared__ unsigned short Tl[BJ * TI];    // T[j][i], chunk-swizzled

    const int tid  = threadIdx.x;
    const int wave = tid >> 6;
    const int lane = tid & 63;
    const int l15  = lane & 15, lq = lane >> 4;
    const int lrow = lane >> 3, ls = lane & 7;
    const int j0    = blockIdx.x * BJ;
    const int ibase = blockIdx.y * IR;

    // phase-A wave split: 2(j) x 2(i); wave tile 32j x 64i
    const int waMa = (wave >> 1) * 32;   // RT_A = 2
    const int waNa = (wave & 1) * 64;    // CT_A = 4
    // phase-B: wave w owns p in [64w, 64w+64); RT_B = 4, CT_B = 4 (all 64 j)
    const int waPb = wave * 64;

    // hoist Z for this block's j rows (phase-A C rows)
    int zaj[2][4];
#pragma unroll
    for (int r = 0; r < 2; ++r)
#pragma unroll
        for (int reg = 0; reg < 4; ++reg)
            zaj[r][reg] = Z[j0 + waMa + r * 16 + lq * 4 + reg];

    f32x4 accY[4][4];
#pragma unroll
    for (int r = 0; r < 4; ++r)
#pragma unroll
        for (int c = 0; c < 4; ++c)
            accY[r][c] = (f32x4){0.f, 0.f, 0.f, 0.f};

#pragma unroll 1
    for (int it = 0; it < IR / TI; ++it) {
        const int i1 = ibase + it * TI;

        // ---------------- phase A: T = masked (desc . X^T)^2 ----------------
        f32x4 accT[2][4];
#pragma unroll
        for (int r = 0; r < 2; ++r)
#pragma unroll
            for (int c = 0; c < 4; ++c)
                accT[r][c] = (f32x4){0.f, 0.f, 0.f, 0.f};

#pragma unroll 1
        for (int k0 = 0; k0 < DF; k0 += BK) {
            __syncthreads();   // tA/tB free (also separates Tl reads from next writes)
            // stage (BJ + TI)/8 = 24 row-chunks, 6 per wave; 16B per lane
#pragma unroll
            for (int itc = 0; itc < 6; ++itc) {
                int cb = wave + itc * 4;
                bool isB = cb >= (BJ / 8);
                int cb2 = isB ? cb - BJ / 8 : cb;
                int row = cb2 * 8 + lrow;
                int g = ls ^ (row & 7);
                const unsigned short* gp = isB
                    ? Xb + (size_t)(i1 + row) * DF + (size_t)(k0 + g * 8)
                    : Db + (size_t)(j0 + row) * DF + (size_t)(k0 + g * 8);
                unsigned short* lp = (isB ? tB : tA) + cb2 * (8 * BK);
                __builtin_amdgcn_global_load_lds(
                    (const __attribute__((address_space(1))) void*)gp,
                    (__attribute__((address_space(3))) void*)lp,
                    16, 0, 0);
            }
            __syncthreads();
#pragma unroll
            for (int kk = 0; kk < BK; kk += 32) {
                const int cbase = kk >> 3;
                bf16x8 af[2], bfv[4];
#pragma unroll
                for (int r = 0; r < 2; ++r) {
                    int m = waMa + r * 16 + l15;
                    int ch = (cbase + lq) ^ (m & 7);
                    af[r] = *(const bf16x8*)&tA[m * BK + ch * 8];
                }
#pragma unroll
                for (int c = 0; c < 4; ++c) {
                    int n = waNa + c * 16 + l15;
                    int ch = (cbase + lq) ^ (n & 7);
                    bfv[c] = *(const bf16x8*)&tB[n * BK + ch * 8];
                }
#pragma unroll
                for (int r = 0; r < 2; ++r)
#pragma unroll
                    for (int c = 0; c < 4; ++c)
                        accT[r][c] = __builtin_amdgcn_mfma_f32_16x16x32_bf16(
                            af[r], bfv[c], accT[r][c], 0, 0, 0);
            }
        }

        // ------------- mask + square -> Tl (bf16, chunk-swizzled) -----------
        // element (j, i_local): ushort index = j*TI + ((i>>3) ^ (j&15))*8 + (i&7)
        int zbv[4];
#pragma unroll
        for (int c = 0; c < 4; ++c)
            zbv[c] = Zr[i1 + waNa + c * 16 + l15];
#pragma unroll
        for (int r = 0; r < 2; ++r)
#pragma unroll
            for (int reg = 0; reg < 4; ++reg) {
                int j = waMa + r * 16 + lq * 4 + reg;
                int za = zaj[r][reg];
#pragma unroll
                for (int c = 0; c < 4; ++c) {
                    int i = waNa + c * 16 + l15;
                    float v = accT[r][c][reg];
                    float kv = (za == zbv[c]) ? v * v : 0.0f;
                    Tl[j * TI + (((i >> 3) ^ (j & 15)) << 3) + (i & 7)] = f2bf(kv);
                }
            }
        __syncthreads();   // Tl visible to all waves

        // ---------------- phase B: accY += Alpha . Tl^T ---------------------
#pragma unroll
        for (int ks = 0; ks < TI; ks += 32) {
            bf16x8 afa[4], bfb[4];
#pragma unroll
            for (int rt = 0; rt < 4; ++rt) {
                int p = waPb + rt * 16 + l15;
                size_t gi = (size_t)p * NREF + (size_t)(i1 + ks + lq * 8);
                afa[rt] = *(const bf16x8*)&Ab[gi];
            }
#pragma unroll
            for (int ct = 0; ct < 4; ++ct) {
                int j = ct * 16 + l15;
                int c8 = (ks >> 3) + lq;
                int slot = c8 ^ (j & 15);
                bfb[ct] = *(const bf16x8*)&Tl[j * TI + slot * 8];
            }
#pragma unroll
            for (int rt = 0; rt < 4; ++rt)
#pragma unroll
                for (int ct = 0; ct < 4; ++ct)
                    accY[rt][ct] = __builtin_amdgcn_mfma_f32_16x16x32_bf16(
                        afa[rt], bfb[ct], accY[rt][ct], 0, 0, 0);
        }
        // next iteration's staging barrier separates these Tl reads
        // from the next Tl writes.
    }

    // ---------------- epilogue ----------------
    const int z = blockIdx.y;
#pragma unroll
    for (int rt = 0; rt < 4; ++rt) {
#pragma unroll
        for (int reg = 0; reg < 4; ++reg) {
            int p = waPb + rt * 16 + lq * 4 + reg;
#pragma unroll
            for (int ct = 0; ct < 4; ++ct) {
                int jg = j0 + ct * 16 + l15;
                float v = accY[rt][ct][reg];
                if (z == 0) {
                    outp[(size_t)p * NIN + jg] = v;
                } else {
                    part[(size_t)(z - 1) * P_DIM * NIN + (size_t)p * NIN + jg] = f2bf(v);
                }
            }
        }
    }
}

extern "C" void kernel_launch(void* const* d_in, const int* in_sizes, int n_in,
                              void* d_out, int out_size, void* d_ws, size_t ws_size,
                              hipStream_t stream) {
    const float* Alpha = (const float*)d_in[0];   // [256, 4096]
    const float* X_ref = (const float*)d_in[1];   // [4096, 512]
    const float* desc  = (const float*)d_in[2];   // [8192, 512]
    const int*   Z_ref = (const int*)d_in[3];     // [4096]
    const int*   Z     = (const int*)d_in[4];     // [8192]
    float* out = (float*)d_out;                   // [256, 8192]

    // ws (bf16): Xb 4MB | Db 8MB | Ab 2MB | part 12MB   (no Kt anymore)
    unsigned short* Xb   = (unsigned short*)d_ws;           // 4096*512
    unsigned short* Db   = Xb + (size_t)NREF * DF;          // 8192*512
    unsigned short* Ab   = Db + (size_t)NIN * DF;           // 256*4096
    unsigned short* part = Ab + (size_t)P_DIM * NREF;       // 3 * 256*8192

    cast3<<<4096, 256, 0, stream>>>(
        X_ref, Xb, NREF * DF / 4,
        desc,  Db, NIN * DF / 4,
        Alpha, Ab, P_DIM * NREF / 4);

    dim3 gf(NIN / BJ, ISPLIT);   // (128, 4) = 512 blocks, 2/CU
    fused_y<<<gf, 256, 0, stream>>>(Db, Xb, Ab, Z, Z_ref, out, part);

    reduce3<<<(P_DIM * NIN / 4 + 255) / 256, 256, 0, stream>>>(
        out, part, P_DIM * NIN / 4, (size_t)P_DIM * NIN);
}